// Round 13
// baseline (138.950 us; speedup 1.0000x reference)
//
#include <hip/hip_runtime.h>

// Problem constants: B=4, S=2048, D=768, H=12, HD=64, M=B*S=8192, K=768.
#define LOG2E 1.4426950408889634f
#define QSCALE (0.125f * LOG2E)   // HD^-0.5 * log2(e), folded into Q

typedef __attribute__((ext_vector_type(8))) __bf16 bf8_t;   // MFMA A/B frag (4 VGPR)
typedef __attribute__((ext_vector_type(4))) float f4_t;     // MFMA C/D frag

__device__ __forceinline__ unsigned short f2bf(float f) {
  unsigned int u = __float_as_uint(f);
  u += 0x7fff + ((u >> 16) & 1);          // RNE
  return (unsigned short)(u >> 16);
}

__device__ __forceinline__ void async16(const void* g, void* l) {
  __builtin_amdgcn_global_load_lds(
      (const __attribute__((address_space(1))) void*)g,
      (__attribute__((address_space(3))) void*)l, 16, 0, 0);
}

// XOR swizzle for 128B LDS rows: spreads 16 consecutive (or kt-permuted) rows
// over 8 distinct 16B slots -> 2-way conflict (free). Involution on 16B units.
__device__ __forceinline__ int swm(int r) {
  return ((r & 3) << 4) | ((r & 8) << 3);
}
__device__ __forceinline__ int swzoff(int row, int cb) {
  return (row << 7) + (cb ^ swm(row));
}

// ---------------- fp32 -> bf16 conversion (4 weight matrices only) ----------------
__global__ void cvt4_kernel(const float* __restrict__ s0, const float* __restrict__ s1,
                            const float* __restrict__ s2, const float* __restrict__ s3,
                            unsigned short* __restrict__ d0, unsigned short* __restrict__ d1,
                            unsigned short* __restrict__ d2, unsigned short* __restrict__ d3,
                            int n4) {
  int z = blockIdx.y;
  const float* s = (z == 0) ? s0 : (z == 1) ? s1 : (z == 2) ? s2 : s3;
  unsigned short* d = (z == 0) ? d0 : (z == 1) ? d1 : (z == 2) ? d2 : d3;
  int i = blockIdx.x * blockDim.x + threadIdx.x;
  int stride = gridDim.x * blockDim.x;
  for (; i < n4; i += stride) {
    float4 v = ((const float4*)s)[i];
    ushort4 o;
    o.x = f2bf(v.x); o.y = f2bf(v.y); o.z = f2bf(v.z); o.w = f2bf(v.w);
    ((ushort4*)d)[i] = o;
  }
}

// ---------------- fused QKV projection: x read f32, converted in-kernel ----------
// Grid 2304 = 128 mt x 18 nt (0-5 Q, 6-11 K, 12-17 V). Unified geometry:
// A = W (i = d-tile 128, bf16, global_load_lds, swm-preswizzled source);
// B = x (j = s-tile 64, f32): reg-stage 16 f32/thread -> cvt_pk -> swizzled
// ds_write_b128 (same swm involution the frag reads use). LDS 48KB -> 3 blk/CU.
// Q/K epilogue: lsT[s][d] chunk-xor transpose -> [B,H,S,64] 16B stores.
// V epilogue:   lsT[d][s] (144B pitch) -> [B,H,64,S] 16B stores.
__global__ __launch_bounds__(256) void proj_qkv(
    const float* __restrict__ xf,
    const unsigned short* __restrict__ wq,
    const unsigned short* __restrict__ wk,
    const unsigned short* __restrict__ wv,
    const float* __restrict__ bq, const float* __restrict__ bk,
    const float* __restrict__ bv,
    unsigned short* __restrict__ qo, unsigned short* __restrict__ ko,
    unsigned short* __restrict__ vto) {
  __shared__ char ls[49152];
  const int bx = (blockIdx.x & 7) * 288 + (blockIdx.x >> 3);   // 2304 = 8*288
  const int mt = bx / 18, nt = bx % 18;
  const int sec = nt / 6, nn = nt % 6;
  const int i0 = nn * 128;   // d-range base
  const int j0 = mt * 64;    // s-range base
  const unsigned short* A = (sec == 0) ? wq : (sec == 1) ? wk : wv;

  const int tid = threadIdx.x, l = tid & 63;
  const int wi = (tid >> 6) >> 1, wj = (tid >> 6) & 1;

  // ---- B-side f32 staging: thread covers 32 bf16-bytes (16 k) of one row ----
  const int xrow = tid >> 2;            // s local 0..63
  const int xcb = (tid & 3) * 32;       // bf16 byte col {0,32,64,96}
  const float* xbase = xf + (size_t)(j0 + xrow) * 768 + (xcb >> 1);
  float4 xr0, xr1, xr2, xr3;
  auto xload = [&](int k0) {
    const float4* g = (const float4*)(xbase + k0);
    xr0 = g[0]; xr1 = g[1]; xr2 = g[2]; xr3 = g[3];
  };
  auto pk2 = [](float lo, float hi) -> unsigned {
    return (unsigned)f2bf(lo) | ((unsigned)f2bf(hi) << 16);
  };
  auto xwrite = [&](int buf) {
    char* dB = ls + buf * 24576 + 16384 + (xrow << 7);
    uint4 w0{pk2(xr0.x, xr0.y), pk2(xr0.z, xr0.w),
             pk2(xr1.x, xr1.y), pk2(xr1.z, xr1.w)};
    uint4 w1{pk2(xr2.x, xr2.y), pk2(xr2.z, xr2.w),
             pk2(xr3.x, xr3.y), pk2(xr3.z, xr3.w)};
    *(uint4*)(dB + (xcb ^ swm(xrow))) = w0;
    *(uint4*)(dB + ((xcb + 16) ^ swm(xrow))) = w1;
  };
  auto wstage = [&](int buf, int k0) {
    char* dA = ls + buf * 24576;
#pragma unroll
    for (int u = 0; u < 4; ++u) {   // A: 128 rows x 64 cols = 16KB
      int p = (u * 256 + tid) * 16;
      int r = p >> 7, c = (p & 127) ^ swm(r);
      async16((const char*)A + ((size_t)(i0 + r) * 768 + k0) * 2 + c, dA + p);
    }
  };

  f4_t acc[4][2] = {};
  xload(0);
  wstage(0, 0);
  xwrite(0);
  __syncthreads();   // drains async16 + ds_writes: tile 0 ready
  for (int kk = 0; kk < 12; ++kk) {
    const int buf = kk & 1;
    if (kk < 11) {                     // issue next-tile loads (hide under compute)
      xload((kk + 1) * 64);
      wstage(buf ^ 1, (kk + 1) * 64);
    }
    const char* lsA = ls + buf * 24576;
    const char* lsB = lsA + 16384;
#pragma unroll
    for (int ks = 0; ks < 2; ++ks) {
      bf8_t af[4], bfr[2];
#pragma unroll
      for (int mi = 0; mi < 4; ++mi)
        af[mi] = *(const bf8_t*)(lsA + swzoff(wi * 64 + mi * 16 + (l & 15),
                                              ks * 64 + ((l >> 4) << 4)));
#pragma unroll
      for (int nj = 0; nj < 2; ++nj)
        bfr[nj] = *(const bf8_t*)(lsB + swzoff(wj * 32 + nj * 16 + (l & 15),
                                               ks * 64 + ((l >> 4) << 4)));
      __builtin_amdgcn_s_setprio(1);
#pragma unroll
      for (int mi = 0; mi < 4; ++mi)
#pragma unroll
        for (int nj = 0; nj < 2; ++nj)
          acc[mi][nj] = __builtin_amdgcn_mfma_f32_16x16x32_bf16(
              af[mi], bfr[nj], acc[mi][nj], 0, 0, 0);
      __builtin_amdgcn_s_setprio(0);
    }
    if (kk < 11) xwrite(buf ^ 1);   // buf^1 readers passed the previous barrier
    __syncthreads();                // xwrite visible + async16 drained + reads done
  }

  if (sec < 2) {
    // ---- Q/K epilogue: acc -> lsT[s][d] (chunk-XOR), bias+scale, 16B stores ----
#pragma unroll
    for (int mi = 0; mi < 4; ++mi) {
#pragma unroll
      for (int nj = 0; nj < 2; ++nj) {
        int ib = wi * 64 + mi * 16 + ((l >> 4) << 2);   // d local (4 consecutive)
        int j  = wj * 32 + nj * 16 + (l & 15);          // s local
        f4_t v = acc[mi][nj];
        const float* bias = sec ? bk : bq;
        float sc = sec ? 1.0f : QSCALE;
        float4 bs = *(const float4*)(bias + i0 + ib);
        ushort4 o;
        o.x = f2bf((v[0] + bs.x) * sc);
        o.y = f2bf((v[1] + bs.y) * sc);
        o.z = f2bf((v[2] + bs.z) * sc);
        o.w = f2bf((v[3] + bs.w) * sc);
        int chunk = (ib >> 3) ^ (j & 15);
        *(ushort4*)(ls + j * 256 + chunk * 16 + ((ib & 7) << 1)) = o;
      }
    }
    __syncthreads();
    const int row = tid >> 2, q4 = tid & 3;
    int sg = mt * 64 + row;
    int b = sg >> 11, s = sg & 2047;
    unsigned short* base = sec ? ko : qo;
#pragma unroll
    for (int cc = 0; cc < 4; ++cc) {
      int cb = q4 * 4 + cc;
      uint4 v = *(const uint4*)(ls + row * 256 + ((cb ^ (row & 15)) << 4));
      int h = nn * 2 + (cb >> 3);
      *(uint4*)(base + (((size_t)(b * 12 + h) * 2048 + s) << 6) + (cb & 7) * 8) = v;
    }
  } else {
    // ---- V epilogue: acc -> lsT[d][s] (144B pitch), bias by d, 16B stores ----
#pragma unroll
    for (int mi = 0; mi < 4; ++mi) {
#pragma unroll
      for (int nj = 0; nj < 2; ++nj) {
        int ib = wi * 64 + mi * 16 + ((l >> 4) << 2);   // d local
        int j  = wj * 32 + nj * 16 + (l & 15);          // s local
        f4_t v = acc[mi][nj];
        float4 bs = *(const float4*)(bv + i0 + ib);
#pragma unroll
        for (int e = 0; e < 4; ++e) {
          float b4 = (e == 0) ? bs.x : (e == 1) ? bs.y : (e == 2) ? bs.z : bs.w;
          *(unsigned short*)(ls + (ib + e) * 144 + j * 2) = f2bf(v[e] + b4);
        }
      }
    }
    __syncthreads();
    const int d = tid >> 1, half = tid & 1;   // d local 0..127
    int h = nn * 2 + (d >> 6), dh = d & 63;
    int b = mt >> 5;
    int sl = (mt & 31) * 64 + half * 32;
    unsigned short* dst = vto + ((size_t)((b * 12 + h) * 64 + dh)) * 2048 + sl;
    const char* src = ls + d * 144 + half * 64;
#pragma unroll
    for (int c = 0; c < 4; ++c)
      *(uint4*)(dst + c * 8) = *(const uint4*)(src + c * 16);
  }
}

// ---------------- all-bf16 GEMM core (proj_o): 128(i) x 64(j), counted vmcnt ----
__device__ __forceinline__ void gemm_core64(const unsigned short* __restrict__ A,
                                            const unsigned short* __restrict__ Bm,
                                            int i0, int j0, char* ls,
                                            f4_t (&acc)[4][2]) {
  const int tid = threadIdx.x, l = tid & 63;
  const int wi = (tid >> 6) >> 1, wj = (tid >> 6) & 1;
  auto stage = [&](int buf, int k0) {
    char* dA = ls + buf * 24576;
    char* dB = dA + 16384;
#pragma unroll
    for (int u = 0; u < 4; ++u) {   // A: 128 rows x 64 cols = 16KB
      int p = (u * 256 + tid) * 16;
      int r = p >> 7, c = (p & 127) ^ swm(r);
      async16((const char*)A + ((size_t)(i0 + r) * 768 + k0) * 2 + c, dA + p);
    }
#pragma unroll
    for (int u = 0; u < 2; ++u) {   // B: 64 rows = 8KB
      int p = (u * 256 + tid) * 16;
      int r = p >> 7, c = (p & 127) ^ swm(r);
      async16((const char*)Bm + ((size_t)(j0 + r) * 768 + k0) * 2 + c, dB + p);
    }
  };
  stage(0, 0);
  for (int kk = 0; kk < 12; ++kk) {
    if (kk < 11) {
      stage((kk + 1) & 1, (kk + 1) * 64);   // prefetch next K-step (stays in flight)
      asm volatile("s_waitcnt vmcnt(6)" ::: "memory");   // stage(kk) complete
    } else {
      asm volatile("s_waitcnt vmcnt(0)" ::: "memory");
    }
    __builtin_amdgcn_s_barrier();           // all waves' stage(kk) loads done
    const char* lsA = ls + (kk & 1) * 24576;
    const char* lsB = lsA + 16384;
#pragma unroll
    for (int ks = 0; ks < 2; ++ks) {
      bf8_t af[4], bfr[2];
#pragma unroll
      for (int mi = 0; mi < 4; ++mi)
        af[mi] = *(const bf8_t*)(lsA + swzoff(wi * 64 + mi * 16 + (l & 15),
                                              ks * 64 + ((l >> 4) << 4)));
#pragma unroll
      for (int nj = 0; nj < 2; ++nj)
        bfr[nj] = *(const bf8_t*)(lsB + swzoff(wj * 32 + nj * 16 + (l & 15),
                                               ks * 64 + ((l >> 4) << 4)));
      __builtin_amdgcn_s_setprio(1);
#pragma unroll
      for (int mi = 0; mi < 4; ++mi)
#pragma unroll
        for (int nj = 0; nj < 2; ++nj)
          acc[mi][nj] = __builtin_amdgcn_mfma_f32_16x16x32_bf16(
              af[mi], bfr[nj], acc[mi][nj], 0, 0, 0);
      __builtin_amdgcn_s_setprio(0);
    }
    __builtin_amdgcn_s_barrier();           // reads done before buf overwrite
  }
}

// ---------------- output projection: out = attn @ Wo^T + bo (fp32 out) ----------
__global__ __launch_bounds__(256) void proj_o(
    const unsigned short* __restrict__ attnb, const unsigned short* __restrict__ wo,
    const float* __restrict__ bo, float* __restrict__ outp) {
  __shared__ char ls[49152];
  const int bx = (blockIdx.x & 7) * 96 + (blockIdx.x >> 3);  // 768 = 8*96
  const int it = bx % 6, jt = bx / 6;
  const int i0 = it * 128, j0 = jt * 64;
  f4_t acc[4][2] = {};
  gemm_core64(wo, attnb, i0, j0, ls, acc);
  const int tid = threadIdx.x, l = tid & 63;
  const int wi = (tid >> 6) >> 1, wj = (tid >> 6) & 1;
#pragma unroll
  for (int mi = 0; mi < 4; ++mi) {
#pragma unroll
    for (int nj = 0; nj < 2; ++nj) {
      int ib = i0 + wi * 64 + mi * 16 + ((l >> 4) << 2);  // n, 4 consecutive
      int j  = j0 + wj * 32 + nj * 16 + (l & 15);         // m
      float4 bs = *(const float4*)(bo + ib);
      float4 o;
      o.x = acc[mi][nj][0] + bs.x;
      o.y = acc[mi][nj][1] + bs.y;
      o.z = acc[mi][nj][2] + bs.z;
      o.w = acc[mi][nj][3] + bs.w;
      *(float4*)(outp + (size_t)j * 768 + ib) = o;
    }
  }
}

// ---------------- flash attention (R6 structure — best measured) ----------------
// Block: 128 q rows of one (b,h); 8 waves = 4 q-waves (32 q each, qt=2) x 2 KV-halves.
// Wave half h processes tiles 2i+h (i=0..15); each K/V tile read by only 4 waves.
// 4-slot LDS ring (64KB): pair {2i,2i+1} in slots {(i&1)*2, (i&1)*2+1}; one barrier
// per iteration. No max-tracking (|s| bounded in log2 domain): p = exp2(s) exact;
// row-sums via ones-MFMA. KV-split combine: O = O_h0+O_h1, l = l_h0+l_h1 (LDS swap).
__global__ __launch_bounds__(512) void attn_kernel(
    const unsigned short* __restrict__ qg,
    const unsigned short* __restrict__ kg,
    const unsigned short* __restrict__ vtg,
    unsigned short* __restrict__ attnb) {
  __shared__ char ls[65536];   // slot s: K at s*16384, V at s*16384+8192
  const int tid = threadIdx.x, l = tid & 63, w = tid >> 6;   // w in 0..7
  const int qw = w & 3, hf = w >> 2;
  // XCD-aware 1D swizzle: 768 = 8*96; groups all 16 q-blocks of a bh on one XCD.
  const int swz = (blockIdx.x & 7) * 96 + (blockIdx.x >> 3);
  const int q0 = (swz & 15) * 128;
  const int bh = swz >> 4;
  const size_t qkbase = (size_t)bh * 2048 * 64;
  const size_t vtbase = (size_t)bh * 64 * 2048;

  // ---- stage Q tile (16KB) into ls[0:16K) ----
#pragma unroll
  for (int u = 0; u < 2; ++u) {
    int p = (u * 512 + tid) * 16;
    int r = p >> 7, cb = p & 127;
    int c = cb ^ swm(r);
    async16((const char*)qg + (qkbase + (size_t)(q0 + r) * 64) * 2 + c, ls + p);
  }
  __syncthreads();
  bf8_t qf[2][2];   // [qt][ks]
#pragma unroll
  for (int qt = 0; qt < 2; ++qt)
#pragma unroll
    for (int ks = 0; ks < 2; ++ks)
      qf[qt][ks] = *(const bf8_t*)(ls + swzoff(qw * 32 + qt * 16 + (l & 15),
                                               ks * 64 + ((l >> 4) << 4)));
  __syncthreads();   // Q consumed; region reusable as KV slots

  // ---- staging thread-map: 512 thr x 16B = one 8KB tile ----
  const int p16 = tid * 16;
  const int sr = p16 >> 7;
  const int sc = (p16 & 127) ^ swm(sr);
  // stage tiles 0,1 into slots 0,1
  async16((const char*)kg + (qkbase + (size_t)sr * 64) * 2 + sc, ls + p16);
  async16((const char*)vtg + (vtbase + (size_t)sr * 2048) * 2 + sc,
          ls + 8192 + p16);
  async16((const char*)kg + (qkbase + (size_t)(64 + sr) * 64) * 2 + sc,
          ls + 16384 + p16);
  async16((const char*)vtg + (vtbase + (size_t)sr * 2048 + 64) * 2 + sc,
          ls + 16384 + 8192 + p16);
  // prefetch pointers for tiles 2 (a) and 3 (b)
  const char* gKa = (const char*)kg + (qkbase + (size_t)(128 + sr) * 64) * 2 + sc;
  const char* gVa = (const char*)vtg + (vtbase + (size_t)sr * 2048 + 128) * 2 + sc;
  const char* gKb = gKa + 8192;
  const char* gVb = gVa + 128;
  __syncthreads();

  // hoisted LDS read offsets (invariant across tiles)
  int koff[4][2];
#pragma unroll
  for (int kt = 0; kt < 4; ++kt) {
    int i = l & 15;
    int row = ((kt >> 1) << 5) + ((kt & 1) << 2) + ((i >> 2) << 3) + (i & 3);
#pragma unroll
    for (int ks = 0; ks < 2; ++ks)
      koff[kt][ks] = swzoff(row, ks * 64 + ((l >> 4) << 4));
  }
  int voff[4][2];
#pragma unroll
  for (int dt = 0; dt < 4; ++dt)
#pragma unroll
    for (int ks = 0; ks < 2; ++ks)
      voff[dt][ks] = swzoff(dt * 16 + (l & 15), ks * 64 + ((l >> 4) << 4));

  bf8_t onesf;
#pragma unroll
  for (int e = 0; e < 8; ++e) onesf[e] = (__bf16)1.0f;

  f4_t acc[4][2] = {};      // O^T (partial, this kv-half): [dt][qt]
  f4_t accs[2] = {};        // row-sum accumulator (all 4 regs equal)

  for (int i = 0; i < 16; ++i) {
    // stage next pair {2i+2, 2i+3} into the other slot pair
    if (i < 15) {
      char* dst = ls + (((i + 1) & 1) * 2) * 16384;
      async16(gKa, dst + p16);
      async16(gVa, dst + 8192 + p16);
      async16(gKb, dst + 16384 + p16);
      async16(gVb, dst + 16384 + 8192 + p16);
      gKa += 16384; gKb += 16384;   // 2 tiles * 64 rows * 128B
      gVa += 256;   gVb += 256;     // 2 tiles * 64 cols * 2B
    }
    const char* bK = ls + ((i & 1) * 2 + hf) * 16384;
    const char* bV = bK + 8192;

    // ---- QK^T (S^T) with permuted K-row feed ----
    f4_t sacc[4][2] = {};
    __builtin_amdgcn_s_setprio(1);
#pragma unroll
    for (int kt = 0; kt < 4; ++kt)
#pragma unroll
      for (int ks = 0; ks < 2; ++ks) {
        bf8_t a = *(const bf8_t*)(bK + koff[kt][ks]);
#pragma unroll
        for (int qt = 0; qt < 2; ++qt)
          sacc[kt][qt] = __builtin_amdgcn_mfma_f32_16x16x32_bf16(
              a, qf[qt][ks], sacc[kt][qt], 0, 0, 0);
      }
    __builtin_amdgcn_s_setprio(0);
    // lane holds, per qt: s for kv = 32*ks + 8*(l>>4) + (4*(kt&1)+j), col q=l&15

    // ---- softmax numerator: p = exp2(s) directly (no max subtraction) ----
    bf8_t pf[2][2];   // [ks][qt]
#pragma unroll
    for (int qt = 0; qt < 2; ++qt)
#pragma unroll
      for (int ks = 0; ks < 2; ++ks)
#pragma unroll
        for (int e = 0; e < 8; ++e)
          pf[ks][qt][e] =
              (__bf16)__builtin_amdgcn_exp2f(sacc[2 * ks + (e >> 2)][qt][e & 3]);

    // ---- PV: O^T += V^T-rows x P ; row-sums += ones x P ----
    __builtin_amdgcn_s_setprio(1);
#pragma unroll
    for (int dt = 0; dt < 4; ++dt) {
      bf8_t av0 = *(const bf8_t*)(bV + voff[dt][0]);
      bf8_t av1 = *(const bf8_t*)(bV + voff[dt][1]);
#pragma unroll
      for (int qt = 0; qt < 2; ++qt) {
        acc[dt][qt] = __builtin_amdgcn_mfma_f32_16x16x32_bf16(av0, pf[0][qt],
                                                              acc[dt][qt], 0, 0, 0);
        acc[dt][qt] = __builtin_amdgcn_mfma_f32_16x16x32_bf16(av1, pf[1][qt],
                                                              acc[dt][qt], 0, 0, 0);
      }
    }
#pragma unroll
    for (int qt = 0; qt < 2; ++qt) {
      accs[qt] = __builtin_amdgcn_mfma_f32_16x16x32_bf16(onesf, pf[0][qt],
                                                         accs[qt], 0, 0, 0);
      accs[qt] = __builtin_amdgcn_mfma_f32_16x16x32_bf16(onesf, pf[1][qt],
                                                         accs[qt], 0, 0, 0);
    }
    __builtin_amdgcn_s_setprio(0);
    __syncthreads();   // pair consumed by all waves; staged pair drained
  }

  // ---- kv-split combine: h1 writes partials to LDS, h0 adds + writes out ----
  char* reg_ = ls + qw * 8704;   // per-qw region: 8KB acc + 512B sums
  if (hf) {
#pragma unroll
    for (int dt = 0; dt < 4; ++dt)
#pragma unroll
      for (int qt = 0; qt < 2; ++qt)
        *(f4_t*)(reg_ + (((dt * 2 + qt) * 64) + l) * 16) = acc[dt][qt];
    *(float2*)(reg_ + 8192 + l * 8) = float2{accs[0][0], accs[1][0]};
  }
  __syncthreads();
  if (!hf) {
    const int bb = bh / 12, h = bh % 12;
    float2 os = *(const float2*)(reg_ + 8192 + l * 8);
    float inv0 = 1.0f / (accs[0][0] + os.x);
    float inv1 = 1.0f / (accs[1][0] + os.y);
#pragma unroll
    for (int qt = 0; qt < 2; ++qt) {
      float inv = qt ? inv1 : inv0;
      int s = q0 + qw * 32 + qt * 16 + (l & 15);
#pragma unroll
      for (int dt = 0; dt < 4; ++dt) {
        f4_t other = *(const f4_t*)(reg_ + (((dt * 2 + qt) * 64) + l) * 16);
        int dg = h * 64 + dt * 16 + ((l >> 4) << 2);
        ushort4 o;
        o.x = f2bf((acc[dt][qt][0] + other[0]) * inv);
        o.y = f2bf((acc[dt][qt][1] + other[1]) * inv);
        o.z = f2bf((acc[dt][qt][2] + other[2]) * inv);
        o.w = f2bf((acc[dt][qt][3] + other[3]) * inv);
        *(ushort4*)(attnb + ((size_t)(bb * 2048 + s)) * 768 + dg) = o;
      }
    }
  }
}

extern "C" void kernel_launch(void* const* d_in, const int* in_sizes, int n_in,
                              void* d_out, int out_size, void* d_ws, size_t ws_size,
                              hipStream_t stream) {
  const float* x  = (const float*)d_in[0];
  const float* Wq = (const float*)d_in[1];
  const float* bq = (const float*)d_in[2];
  const float* Wk = (const float*)d_in[3];
  const float* bk = (const float*)d_in[4];
  const float* Wv = (const float*)d_in[5];
  const float* bv = (const float*)d_in[6];
  const float* Wo = (const float*)d_in[7];
  const float* bo = (const float*)d_in[8];

  const size_t XB_ELEMS = (size_t)8192 * 768;   // 6291456
  const size_t W_ELEMS  = (size_t)768 * 768;    // 589824
  unsigned short* wqb = (unsigned short*)d_ws;
  unsigned short* wkb = wqb + W_ELEMS;
  unsigned short* wvb = wkb + W_ELEMS;
  unsigned short* wob = wvb + W_ELEMS;
  unsigned short* qb  = wob + W_ELEMS;
  unsigned short* kb  = qb  + XB_ELEMS;
  unsigned short* vtb = kb  + XB_ELEMS;
  unsigned short* attnb = vtb + XB_ELEMS;

  cvt4_kernel<<<dim3(144, 4), 256, 0, stream>>>(Wq, Wk, Wv, Wo,
                                                wqb, wkb, wvb, wob,
                                                (int)(W_ELEMS / 4));
  proj_qkv<<<2304, 256, 0, stream>>>(x, wqb, wkb, wvb, bq, bk, bv, qb, kb, vtb);
  attn_kernel<<<768, 512, 0, stream>>>(qb, kb, vtb, attnb);
  proj_o<<<768, 256, 0, stream>>>(attnb, wob, bo, (float*)d_out);
}

// Round 15
// 129.239 us; speedup vs baseline: 1.0751x; 1.0751x over previous
//
#include <hip/hip_runtime.h>

// Problem constants: B=4, S=2048, D=768, H=12, HD=64, M=B*S=8192, K=768.
#define LOG2E 1.4426950408889634f
#define QSCALE (0.125f * LOG2E)   // HD^-0.5 * log2(e), folded into Q

typedef __attribute__((ext_vector_type(8))) __bf16 bf8_t;   // MFMA A/B frag (4 VGPR)
typedef __attribute__((ext_vector_type(4))) float f4_t;     // MFMA C/D frag

__device__ __forceinline__ unsigned short f2bf(float f) {
  unsigned int u = __float_as_uint(f);
  u += 0x7fff + ((u >> 16) & 1);          // RNE
  return (unsigned short)(u >> 16);
}

__device__ __forceinline__ void async16(const void* g, void* l) {
  __builtin_amdgcn_global_load_lds(
      (const __attribute__((address_space(1))) void*)g,
      (__attribute__((address_space(3))) void*)l, 16, 0, 0);
}

// XOR swizzle for 128B LDS rows: spreads 16 consecutive (or kt-permuted) rows
// over 8 distinct 16B slots -> 2-way conflict (free). Involution on 16B units.
__device__ __forceinline__ int swm(int r) {
  return ((r & 3) << 4) | ((r & 8) << 3);
}
__device__ __forceinline__ int swzoff(int row, int cb) {
  return (row << 7) + (cb ^ swm(row));
}

// ---------------- fp32 -> bf16 conversion (x + 4 weights, one launch) ----------------
__global__ void cvt_multi(const float* __restrict__ x,
                          const float* __restrict__ w0, const float* __restrict__ w1,
                          const float* __restrict__ w2, const float* __restrict__ w3,
                          unsigned short* __restrict__ xb,
                          unsigned short* __restrict__ d0, unsigned short* __restrict__ d1,
                          unsigned short* __restrict__ d2, unsigned short* __restrict__ d3) {
  const int NX = 1572864;   // x float4 count
  const int NW = 147456;    // per-weight float4 count
  const int total = NX + 4 * NW;
  int i = blockIdx.x * blockDim.x + threadIdx.x;
  int stride = gridDim.x * blockDim.x;
  for (; i < total; i += stride) {
    const float* s;
    unsigned short* d;
    int off;
    if (i < NX) {
      s = x; d = xb; off = i;
    } else {
      int j = i - NX;
      int wsel = j / NW;
      off = j - wsel * NW;
      s = (wsel == 0) ? w0 : (wsel == 1) ? w1 : (wsel == 2) ? w2 : w3;
      d = (wsel == 0) ? d0 : (wsel == 1) ? d1 : (wsel == 2) ? d2 : d3;
    }
    float4 v = ((const float4*)s)[off];
    ushort4 o;
    o.x = f2bf(v.x); o.y = f2bf(v.y); o.z = f2bf(v.z); o.w = f2bf(v.w);
    ((ushort4*)d)[off] = o;
  }
}

// ------------- shared NT-GEMM core: 128(i) x 64(j), counted-vmcnt dbuf -------------
// D[i][j] = sum_k A[i][k] * Bm[j][k], K=768, BK=64, 4 waves: wi 2x64(i), wj 2x32(j).
// C/D layout: col(j) = lane&15, row(i) = (lane>>4)*4 + reg.
// ls: buf b at b*24576 (A 16KB + B 8KB); 48KB total -> 3 blocks/CU.
// NOTE (R14 lesson): the counted-vmcnt/raw-barrier protocol needs explicit
// scheduling fences — sched_barrier(0) after each s_waitcnt (rule #18); the
// setprio pair around the MFMAs additionally pins the cluster (removing it
// alone produced a data race in R14).
__device__ __forceinline__ void gemm_core64(const unsigned short* __restrict__ A,
                                            const unsigned short* __restrict__ Bm,
                                            int i0, int j0, char* ls,
                                            f4_t (&acc)[4][2]) {
  const int tid = threadIdx.x, l = tid & 63;
  const int wi = (tid >> 6) >> 1, wj = (tid >> 6) & 1;
  auto stage = [&](int buf, int k0) {
    char* dA = ls + buf * 24576;
    char* dB = dA + 16384;
#pragma unroll
    for (int u = 0; u < 4; ++u) {   // A: 128 rows x 64 cols = 16KB
      int p = (u * 256 + tid) * 16;
      int r = p >> 7, c = (p & 127) ^ swm(r);
      async16((const char*)A + ((size_t)(i0 + r) * 768 + k0) * 2 + c, dA + p);
    }
#pragma unroll
    for (int u = 0; u < 2; ++u) {   // B: 64 rows = 8KB
      int p = (u * 256 + tid) * 16;
      int r = p >> 7, c = (p & 127) ^ swm(r);
      async16((const char*)Bm + ((size_t)(j0 + r) * 768 + k0) * 2 + c, dB + p);
    }
  };
  stage(0, 0);
  for (int kk = 0; kk < 12; ++kk) {
    if (kk < 11) {
      stage((kk + 1) & 1, (kk + 1) * 64);   // prefetch next K-step (stays in flight)
      asm volatile("s_waitcnt vmcnt(6)" ::: "memory");   // stage(kk) complete
    } else {
      asm volatile("s_waitcnt vmcnt(0)" ::: "memory");
    }
    __builtin_amdgcn_sched_barrier(0);      // pin: nothing crosses the waitcnt
    __builtin_amdgcn_s_barrier();           // all waves' stage(kk) loads done
    __builtin_amdgcn_sched_barrier(0);      // pin: reads stay after the barrier
    const char* lsA = ls + (kk & 1) * 24576;
    const char* lsB = lsA + 16384;
#pragma unroll
    for (int ks = 0; ks < 2; ++ks) {
      bf8_t af[4], bfr[2];
#pragma unroll
      for (int mi = 0; mi < 4; ++mi)
        af[mi] = *(const bf8_t*)(lsA + swzoff(wi * 64 + mi * 16 + (l & 15),
                                              ks * 64 + ((l >> 4) << 4)));
#pragma unroll
      for (int nj = 0; nj < 2; ++nj)
        bfr[nj] = *(const bf8_t*)(lsB + swzoff(wj * 32 + nj * 16 + (l & 15),
                                               ks * 64 + ((l >> 4) << 4)));
      __builtin_amdgcn_s_setprio(1);
#pragma unroll
      for (int mi = 0; mi < 4; ++mi)
#pragma unroll
        for (int nj = 0; nj < 2; ++nj)
          acc[mi][nj] = __builtin_amdgcn_mfma_f32_16x16x32_bf16(
              af[mi], bfr[nj], acc[mi][nj], 0, 0, 0);
      __builtin_amdgcn_s_setprio(0);
    }
    __builtin_amdgcn_sched_barrier(0);      // pin: reads complete before barrier
    __builtin_amdgcn_s_barrier();           // reads done before buf overwrite
  }
}

// ---------------- fused QKV projection (128x64 tiles, 2304 blocks) ----------------
// Grid 2304 = 128 mt x 18 nt (0-5 Q, 6-11 K, 12-17 V).
// Q/K (sec<2): A=W (i=d, 128), B=xb (j=s, 64) -> lsT[s][d] -> [B,H,S,64] stores.
// V   (sec=2): A=xb (i=s, 128), B=Wv (j=d, 64) -> lsT[d][s] -> [B,H,64,S] stores.
__global__ __launch_bounds__(256) void proj_qkv(
    const unsigned short* __restrict__ xb,
    const unsigned short* __restrict__ wq,
    const unsigned short* __restrict__ wk,
    const unsigned short* __restrict__ wv,
    const float* __restrict__ bq, const float* __restrict__ bk,
    const float* __restrict__ bv,
    unsigned short* __restrict__ qo, unsigned short* __restrict__ ko,
    unsigned short* __restrict__ vto) {
  __shared__ char ls[49152];
  const int bx = (blockIdx.x & 7) * 288 + (blockIdx.x >> 3);   // 2304 = 8*288
  const int mt = bx / 18, nt = bx % 18;
  const int sec = nt / 6, nn = nt % 6;
  f4_t acc[4][2] = {};
  int i0, j0;
  if (sec < 2) {
    i0 = nn * 128;            // d
    j0 = mt * 64;             // s
    gemm_core64(sec ? wk : wq, xb, i0, j0, ls, acc);
  } else {
    i0 = (mt >> 1) * 128;                 // s
    j0 = (nn * 2 + (mt & 1)) * 64;        // d
    gemm_core64(xb, wv, i0, j0, ls, acc);
  }

  const int tid = threadIdx.x, l = tid & 63;
  const int wi = (tid >> 6) >> 1, wj = (tid >> 6) & 1;
  // ---- acc -> lsT[j][i] (bf16, chunk-XOR swizzle), with bias/scale ----
#pragma unroll
  for (int mi = 0; mi < 4; ++mi) {
#pragma unroll
    for (int nj = 0; nj < 2; ++nj) {
      int ib = wi * 64 + mi * 16 + ((l >> 4) << 2);   // i local (4 consecutive)
      int j  = wj * 32 + nj * 16 + (l & 15);          // j local (0..63)
      f4_t v = acc[mi][nj];
      ushort4 o;
      if (sec < 2) {
        const float* bias = sec ? bk : bq;
        float sc = sec ? 1.0f : QSCALE;
        float4 bs = *(const float4*)(bias + i0 + ib);
        o.x = f2bf((v[0] + bs.x) * sc);
        o.y = f2bf((v[1] + bs.y) * sc);
        o.z = f2bf((v[2] + bs.z) * sc);
        o.w = f2bf((v[3] + bs.w) * sc);
      } else {
        float bvs = bv[j0 + j];
        o.x = f2bf(v[0] + bvs); o.y = f2bf(v[1] + bvs);
        o.z = f2bf(v[2] + bvs); o.w = f2bf(v[3] + bvs);
      }
      int chunk = (ib >> 3) ^ (j & 15);
      *(ushort4*)(ls + j * 256 + chunk * 16 + ((ib & 7) << 1)) = o;
    }
  }
  __syncthreads();
  // ---- lsT rows (64 x 256B) -> coalesced 16B global stores; 4 thr/row ----
  const int row = tid >> 2, q4 = tid & 3;
  if (sec < 2) {
    // row = s local; logical chunk cb -> d = cb*8..cb*8+7 (h = nn*2 + cb>>3)
    int sg = mt * 64 + row;
    int b = sg >> 11, s = sg & 2047;
    unsigned short* base = sec ? ko : qo;
#pragma unroll
    for (int cc = 0; cc < 4; ++cc) {
      int cb = q4 * 4 + cc;
      uint4 v = *(const uint4*)(ls + row * 256 + ((cb ^ (row & 15)) << 4));
      int h = nn * 2 + (cb >> 3);
      *(uint4*)(base + (((size_t)(b * 12 + h) * 2048 + s) << 6) + (cb & 7) * 8) = v;
    }
  } else {
    // row = d local; logical chunk cb -> s local = cb*8..cb*8+7
    int h = nn * 2 + (mt & 1), dh = row;
    int st = mt >> 1;                 // s-tile (128 rows)
    int b = st >> 4;
    int sl = (st & 15) * 128;
    unsigned short* dst0 = vto + ((size_t)((b * 12 + h) * 64 + dh)) * 2048 + sl;
#pragma unroll
    for (int cc = 0; cc < 4; ++cc) {
      int cb = q4 * 4 + cc;
      uint4 v = *(const uint4*)(ls + row * 256 + ((cb ^ (row & 15)) << 4));
      *(uint4*)(dst0 + cb * 8) = v;
    }
  }
}

// ---------------- output projection: out = attn @ Wo^T + bo (fp32 out) ----------
// Tile 128(n) x 64(m) -> 768 blocks (3/CU); shared gemm_core64.
__global__ __launch_bounds__(256) void proj_o(
    const unsigned short* __restrict__ attnb, const unsigned short* __restrict__ wo,
    const float* __restrict__ bo, float* __restrict__ outp) {
  __shared__ char ls[49152];
  const int bx = (blockIdx.x & 7) * 96 + (blockIdx.x >> 3);  // 768 = 8*96
  const int it = bx % 6, jt = bx / 6;
  const int i0 = it * 128, j0 = jt * 64;
  f4_t acc[4][2] = {};
  gemm_core64(wo, attnb, i0, j0, ls, acc);
  const int tid = threadIdx.x, l = tid & 63;
  const int wi = (tid >> 6) >> 1, wj = (tid >> 6) & 1;
#pragma unroll
  for (int mi = 0; mi < 4; ++mi) {
#pragma unroll
    for (int nj = 0; nj < 2; ++nj) {
      int ib = i0 + wi * 64 + mi * 16 + ((l >> 4) << 2);  // n, 4 consecutive
      int j  = j0 + wj * 32 + nj * 16 + (l & 15);         // m
      float4 bs = *(const float4*)(bo + ib);
      float4 o;
      o.x = acc[mi][nj][0] + bs.x;
      o.y = acc[mi][nj][1] + bs.y;
      o.z = acc[mi][nj][2] + bs.z;
      o.w = acc[mi][nj][3] + bs.w;
      *(float4*)(outp + (size_t)j * 768 + ib) = o;
    }
  }
}

// ---------------- flash attention (R6 structure — best measured) ----------------
// Block: 128 q rows of one (b,h); 8 waves = 4 q-waves (32 q each, qt=2) x 2 KV-halves.
// Wave half h processes tiles 2i+h (i=0..15); each K/V tile read by only 4 waves.
// 4-slot LDS ring (64KB): pair {2i,2i+1} in slots {(i&1)*2, (i&1)*2+1}; one barrier
// per iteration. No max-tracking (|s| bounded in log2 domain): p = exp2(s) exact;
// row-sums via ones-MFMA. KV-split combine: O = O_h0+O_h1, l = l_h0+l_h1 (LDS swap).
__global__ __launch_bounds__(512) void attn_kernel(
    const unsigned short* __restrict__ qg,
    const unsigned short* __restrict__ kg,
    const unsigned short* __restrict__ vtg,
    unsigned short* __restrict__ attnb) {
  __shared__ char ls[65536];   // slot s: K at s*16384, V at s*16384+8192
  const int tid = threadIdx.x, l = tid & 63, w = tid >> 6;   // w in 0..7
  const int qw = w & 3, hf = w >> 2;
  // XCD-aware 1D swizzle: 768 = 8*96; groups all 16 q-blocks of a bh on one XCD.
  const int swz = (blockIdx.x & 7) * 96 + (blockIdx.x >> 3);
  const int q0 = (swz & 15) * 128;
  const int bh = swz >> 4;
  const size_t qkbase = (size_t)bh * 2048 * 64;
  const size_t vtbase = (size_t)bh * 64 * 2048;

  // ---- stage Q tile (16KB) into ls[0:16K) ----
#pragma unroll
  for (int u = 0; u < 2; ++u) {
    int p = (u * 512 + tid) * 16;
    int r = p >> 7, cb = p & 127;
    int c = cb ^ swm(r);
    async16((const char*)qg + (qkbase + (size_t)(q0 + r) * 64) * 2 + c, ls + p);
  }
  __syncthreads();
  bf8_t qf[2][2];   // [qt][ks]
#pragma unroll
  for (int qt = 0; qt < 2; ++qt)
#pragma unroll
    for (int ks = 0; ks < 2; ++ks)
      qf[qt][ks] = *(const bf8_t*)(ls + swzoff(qw * 32 + qt * 16 + (l & 15),
                                               ks * 64 + ((l >> 4) << 4)));
  __syncthreads();   // Q consumed; region reusable as KV slots

  // ---- staging thread-map: 512 thr x 16B = one 8KB tile ----
  const int p16 = tid * 16;
  const int sr = p16 >> 7;
  const int sc = (p16 & 127) ^ swm(sr);
  // stage tiles 0,1 into slots 0,1
  async16((const char*)kg + (qkbase + (size_t)sr * 64) * 2 + sc, ls + p16);
  async16((const char*)vtg + (vtbase + (size_t)sr * 2048) * 2 + sc,
          ls + 8192 + p16);
  async16((const char*)kg + (qkbase + (size_t)(64 + sr) * 64) * 2 + sc,
          ls + 16384 + p16);
  async16((const char*)vtg + (vtbase + (size_t)sr * 2048 + 64) * 2 + sc,
          ls + 16384 + 8192 + p16);
  // prefetch pointers for tiles 2 (a) and 3 (b)
  const char* gKa = (const char*)kg + (qkbase + (size_t)(128 + sr) * 64) * 2 + sc;
  const char* gVa = (const char*)vtg + (vtbase + (size_t)sr * 2048 + 128) * 2 + sc;
  const char* gKb = gKa + 8192;
  const char* gVb = gVa + 128;
  __syncthreads();

  // hoisted LDS read offsets (invariant across tiles)
  int koff[4][2];
#pragma unroll
  for (int kt = 0; kt < 4; ++kt) {
    int i = l & 15;
    int row = ((kt >> 1) << 5) + ((kt & 1) << 2) + ((i >> 2) << 3) + (i & 3);
#pragma unroll
    for (int ks = 0; ks < 2; ++ks)
      koff[kt][ks] = swzoff(row, ks * 64 + ((l >> 4) << 4));
  }
  int voff[4][2];
#pragma unroll
  for (int dt = 0; dt < 4; ++dt)
#pragma unroll
    for (int ks = 0; ks < 2; ++ks)
      voff[dt][ks] = swzoff(dt * 16 + (l & 15), ks * 64 + ((l >> 4) << 4));

  bf8_t onesf;
#pragma unroll
  for (int e = 0; e < 8; ++e) onesf[e] = (__bf16)1.0f;

  f4_t acc[4][2] = {};      // O^T (partial, this kv-half): [dt][qt]
  f4_t accs[2] = {};        // row-sum accumulator (all 4 regs equal)

  for (int i = 0; i < 16; ++i) {
    // stage next pair {2i+2, 2i+3} into the other slot pair
    if (i < 15) {
      char* dst = ls + (((i + 1) & 1) * 2) * 16384;
      async16(gKa, dst + p16);
      async16(gVa, dst + 8192 + p16);
      async16(gKb, dst + 16384 + p16);
      async16(gVb, dst + 16384 + 8192 + p16);
      gKa += 16384; gKb += 16384;   // 2 tiles * 64 rows * 128B
      gVa += 256;   gVb += 256;     // 2 tiles * 64 cols * 2B
    }
    const char* bK = ls + ((i & 1) * 2 + hf) * 16384;
    const char* bV = bK + 8192;

    // ---- QK^T (S^T) with permuted K-row feed ----
    f4_t sacc[4][2] = {};
    __builtin_amdgcn_s_setprio(1);
#pragma unroll
    for (int kt = 0; kt < 4; ++kt)
#pragma unroll
      for (int ks = 0; ks < 2; ++ks) {
        bf8_t a = *(const bf8_t*)(bK + koff[kt][ks]);
#pragma unroll
        for (int qt = 0; qt < 2; ++qt)
          sacc[kt][qt] = __builtin_amdgcn_mfma_f32_16x16x32_bf16(
              a, qf[qt][ks], sacc[kt][qt], 0, 0, 0);
      }
    __builtin_amdgcn_s_setprio(0);
    // lane holds, per qt: s for kv = 32*ks + 8*(l>>4) + (4*(kt&1)+j), col q=l&15

    // ---- softmax numerator: p = exp2(s) directly (no max subtraction) ----
    bf8_t pf[2][2];   // [ks][qt]
#pragma unroll
    for (int qt = 0; qt < 2; ++qt)
#pragma unroll
      for (int ks = 0; ks < 2; ++ks)
#pragma unroll
        for (int e = 0; e < 8; ++e)
          pf[ks][qt][e] =
              (__bf16)__builtin_amdgcn_exp2f(sacc[2 * ks + (e >> 2)][qt][e & 3]);

    // ---- PV: O^T += V^T-rows x P ; row-sums += ones x P ----
    __builtin_amdgcn_s_setprio(1);
#pragma unroll
    for (int dt = 0; dt < 4; ++dt) {
      bf8_t av0 = *(const bf8_t*)(bV + voff[dt][0]);
      bf8_t av1 = *(const bf8_t*)(bV + voff[dt][1]);
#pragma unroll
      for (int qt = 0; qt < 2; ++qt) {
        acc[dt][qt] = __builtin_amdgcn_mfma_f32_16x16x32_bf16(av0, pf[0][qt],
                                                              acc[dt][qt], 0, 0, 0);
        acc[dt][qt] = __builtin_amdgcn_mfma_f32_16x16x32_bf16(av1, pf[1][qt],
                                                              acc[dt][qt], 0, 0, 0);
      }
    }
#pragma unroll
    for (int qt = 0; qt < 2; ++qt) {
      accs[qt] = __builtin_amdgcn_mfma_f32_16x16x32_bf16(onesf, pf[0][qt],
                                                         accs[qt], 0, 0, 0);
      accs[qt] = __builtin_amdgcn_mfma_f32_16x16x32_bf16(onesf, pf[1][qt],
                                                         accs[qt], 0, 0, 0);
    }
    __builtin_amdgcn_s_setprio(0);
    __syncthreads();   // pair consumed by all waves; staged pair drained
  }

  // ---- kv-split combine: h1 writes partials to LDS, h0 adds + writes out ----
  char* reg_ = ls + qw * 8704;   // per-qw region: 8KB acc + 512B sums
  if (hf) {
#pragma unroll
    for (int dt = 0; dt < 4; ++dt)
#pragma unroll
      for (int qt = 0; qt < 2; ++qt)
        *(f4_t*)(reg_ + (((dt * 2 + qt) * 64) + l) * 16) = acc[dt][qt];
    *(float2*)(reg_ + 8192 + l * 8) = float2{accs[0][0], accs[1][0]};
  }
  __syncthreads();
  if (!hf) {
    const int bb = bh / 12, h = bh % 12;
    float2 os = *(const float2*)(reg_ + 8192 + l * 8);
    float inv0 = 1.0f / (accs[0][0] + os.x);
    float inv1 = 1.0f / (accs[1][0] + os.y);
#pragma unroll
    for (int qt = 0; qt < 2; ++qt) {
      float inv = qt ? inv1 : inv0;
      int s = q0 + qw * 32 + qt * 16 + (l & 15);
#pragma unroll
      for (int dt = 0; dt < 4; ++dt) {
        f4_t other = *(const f4_t*)(reg_ + (((dt * 2 + qt) * 64) + l) * 16);
        int dg = h * 64 + dt * 16 + ((l >> 4) << 2);
        ushort4 o;
        o.x = f2bf((acc[dt][qt][0] + other[0]) * inv);
        o.y = f2bf((acc[dt][qt][1] + other[1]) * inv);
        o.z = f2bf((acc[dt][qt][2] + other[2]) * inv);
        o.w = f2bf((acc[dt][qt][3] + other[3]) * inv);
        *(ushort4*)(attnb + ((size_t)(bb * 2048 + s)) * 768 + dg) = o;
      }
    }
  }
}

extern "C" void kernel_launch(void* const* d_in, const int* in_sizes, int n_in,
                              void* d_out, int out_size, void* d_ws, size_t ws_size,
                              hipStream_t stream) {
  const float* x  = (const float*)d_in[0];
  const float* Wq = (const float*)d_in[1];
  const float* bq = (const float*)d_in[2];
  const float* Wk = (const float*)d_in[3];
  const float* bk = (const float*)d_in[4];
  const float* Wv = (const float*)d_in[5];
  const float* bv = (const float*)d_in[6];
  const float* Wo = (const float*)d_in[7];
  const float* bo = (const float*)d_in[8];

  const size_t XB_ELEMS = (size_t)8192 * 768;   // 6291456
  const size_t W_ELEMS  = (size_t)768 * 768;    // 589824
  unsigned short* xb  = (unsigned short*)d_ws;
  unsigned short* wqb = xb  + XB_ELEMS;
  unsigned short* wkb = wqb + W_ELEMS;
  unsigned short* wvb = wkb + W_ELEMS;
  unsigned short* wob = wvb + W_ELEMS;
  unsigned short* qb  = wob + W_ELEMS;
  unsigned short* kb  = qb  + XB_ELEMS;
  unsigned short* vtb = kb  + XB_ELEMS;
  unsigned short* attnb = xb;   // alias: xb dead after proj_qkv

  cvt_multi<<<2048, 256, 0, stream>>>(x, Wq, Wk, Wv, Wo,
                                      xb, wqb, wkb, wvb, wob);
  proj_qkv<<<2304, 256, 0, stream>>>(xb, wqb, wkb, wvb, bq, bk, bv, qb, kb, vtb);
  attn_kernel<<<768, 512, 0, stream>>>(qb, kb, vtb, attnb);
  proj_o<<<768, 256, 0, stream>>>(attnb, wob, bo, (float*)d_out);
}